// Round 17
// baseline (456.552 us; speedup 1.0000x reference)
//
#include <hip/hip_runtime.h>
#include <type_traits>

#define NNODES 98304
#define NB 4
#define NX 128
#define FACE (NX * NX)

typedef __attribute__((ext_vector_type(8))) short short8;
typedef __attribute__((ext_vector_type(8))) unsigned short ushort8;
typedef __attribute__((ext_vector_type(4))) float f32x4;

__device__ __forceinline__ float bf2f(unsigned short u) {
  union { unsigned int u; float f; } c; c.u = ((unsigned int)u) << 16; return c.f;
}
__device__ __forceinline__ unsigned short f2bf(float f) {
  union { float f; unsigned int u; } c; c.f = f;
  unsigned int r = 0x7FFFu + ((c.u >> 16) & 1u);
  return (unsigned short)((c.u + r) >> 16);
}
// packed f32x2 -> bf16x2 (RNE); low16 = lo
__device__ __forceinline__ unsigned int cvtpk(float lo, float hi) {
  unsigned int r;
  asm("v_cvt_pk_bf16_f32 %0, %1, %2" : "=v"(r) : "v"(lo), "v"(hi));
  return r;
}

// Analytic 4-neighborhood (verified vs reference _build_neighbors).
__device__ __forceinline__ int4 nbr4(int n) {
  const int base = n & ~(FACE - 1);
  const int i = (n >> 7) & (NX - 1);
  const int j = n & (NX - 1);
  const int iu = (i + NX - 1) & (NX - 1), id = (i + 1) & (NX - 1);
  const int jl = (j + NX - 1) & (NX - 1), jr = (j + 1) & (NX - 1);
  return make_int4(base + (iu << 7) + j, base + (id << 7) + j,
                   base + (i << 7) + jl, base + (i << 7) + jr);
}

// lgkm-only tile barrier: prefetch global loads stay in flight across it.
__device__ __forceinline__ void tile_barrier() {
  asm volatile("s_waitcnt lgkmcnt(0)" ::: "memory");
  __builtin_amdgcn_s_barrier();
  asm volatile("" ::: "memory");
}

// Geometry / residency (round-11 proven values -- the 220us champion).
constexpr int rows_for(int FIN)            { return FIN == 32 ? 64 : 32; }
constexpr int grid_for(int FIN, int SRCK)  { return (FIN == 128 || SRCK == 0) ? 1024 : 1536; }
constexpr int minw_for(int FIN, int SRCK)  { return (FIN == 128 || SRCK == 0) ? 4 : 6; }

// Fused SAGE layer via MFMA: out = relu?( [X | mean4(X)] @ [Ws; Wn] + b ).
// Champion structure + DEPTH-2 prefetch for bf16-source layers (SRCK==1):
// pair loop with named slots pA/pB so each gather's loads are in flight for
// ~2 compute phases before finish() waits on them. L1 (fp32 source, 40-VGPR
// prefetch struct) keeps the proven depth-1 loop.
// SRCK: 0 = fp32 [B, N, FIN]; 1 = bf16 [N, B, sstride] + col offset soff.
// DSTK: 0 = fp32 [B, N, FOUT]; 1 = bf16 [N, B, dstride] + doff.
template<int FIN, int FOUT, int SRCK, int DSTK, bool RELU>
__global__ __launch_bounds__(256, minw_for(FIN, SRCK))
void sage_mfma(const void* __restrict__ srcp, int sstride, int soff,
               void* __restrict__ dstp, int dstride, int doff,
               const float* __restrict__ Ws, const float* __restrict__ Wn,
               const float* __restrict__ bias)
{
  constexpr int ROWS = rows_for(FIN);
  constexpr int GRID = grid_for(FIN, SRCK);
  constexpr int NPT = ROWS / 4;                  // nodes per tile
  constexpr int NTILES = (NNODES * NB) / ROWS;
  constexpr int NT = NTILES / GRID;              // 8 / 4 / 12 / 6 -- exact
  constexpr int NPAIR = NT / 2;                  // even in all SRCK==1 configs
  constexpr int K = 2 * FIN;
  constexpr int KSTEPS = K / 32;
  constexpr int LD = K + 8;                      // +16B pad (2-way conflict, free)
  constexpr int WAVES_N = (FOUT >= 64) ? 4 : 2;
  constexpr int WAVES_M = 4 / WAVES_N;
  constexpr int CF = FOUT / (16 * WAVES_N);
  constexpr int RF = ROWS / (16 * WAVES_M);
  constexpr int CHUNKS = FIN / 8;
  constexpr int ITERS = (ROWS * CHUNKS) / 256;   // 1 or 2 staging groups/thread

  __shared__ unsigned short As[2][ROWS][LD];

  const int tid = threadIdx.x;
  const int wave = tid >> 6, lane = tid & 63;
  const int wn = wave % WAVES_N, wm = wave / WAVES_N;
  const int colbase = wn * (FOUT / WAVES_N);
  const int rowbase = wm * (ROWS / WAVES_M);
  const int fn = lane & 15, fg = lane >> 4;

  // ---- weight fragments (B-operand = [Ws;Wn]), built once per block ----
  short8 Bfrag[KSTEPS][CF];
  float bv[CF];
  #pragma unroll
  for (int ks = 0; ks < KSTEPS; ++ks) {
    const float* wb = (ks * 32 < FIN) ? (Ws + (size_t)(ks * 32) * FOUT)
                                      : (Wn + (size_t)(ks * 32 - FIN) * FOUT);
    #pragma unroll
    for (int cf = 0; cf < CF; ++cf) {
      const int col = colbase + cf * 16 + fn;
      short8 f;
      #pragma unroll
      for (int j = 0; j < 8; ++j)
        f[j] = (short)f2bf(wb[(size_t)(fg * 8 + j) * FOUT + col]);
      Bfrag[ks][cf] = f;
    }
  }
  #pragma unroll
  for (int cf = 0; cf < CF; ++cf) bv[cf] = bias[colbase + cf * 16 + fn];

  struct G0 { float4 s0, s1, a0, a1, b0, b1, c0, c1, d0, d1; };
  struct G1 { ushort8 s, n0, n1, n2, n3; };
  using PG = typename std::conditional<SRCK == 0, G0, G1>::type;

  // issue: analytic neighbors + fire global loads (no waits)
  auto issue = [&](int node0, int it, PG& p) {
    const int g = tid + it * 256;
    const int r = g / CHUNKS;
    const int c = (g - r * CHUNKS) * 8;
    const int n = node0 + (r >> 2);
    const int b = r & 3;
    const int4 nb4 = nbr4(n);
    if constexpr (SRCK == 0) {
      const float* s = (const float*)srcp;
      const float* ps = s + ((size_t)b * NNODES + n) * FIN + c;
      const float* p0 = s + ((size_t)b * NNODES + nb4.x) * FIN + c;
      const float* p1 = s + ((size_t)b * NNODES + nb4.y) * FIN + c;
      const float* p2 = s + ((size_t)b * NNODES + nb4.z) * FIN + c;
      const float* p3 = s + ((size_t)b * NNODES + nb4.w) * FIN + c;
      p.s0 = *(const float4*)ps; p.s1 = *(const float4*)(ps + 4);
      p.a0 = *(const float4*)p0; p.a1 = *(const float4*)(p0 + 4);
      p.b0 = *(const float4*)p1; p.b1 = *(const float4*)(p1 + 4);
      p.c0 = *(const float4*)p2; p.c1 = *(const float4*)(p2 + 4);
      p.d0 = *(const float4*)p3; p.d1 = *(const float4*)(p3 + 4);
    } else {
      const unsigned short* s = (const unsigned short*)srcp;
      auto ld = [&](int nn) {
        return *reinterpret_cast<const ushort8*>(s + ((size_t)nn * NB + b) * sstride + soff + c);
      };
      p.s = ld(n); p.n0 = ld(nb4.x); p.n1 = ld(nb4.y); p.n2 = ld(nb4.z); p.n3 = ld(nb4.w);
    }
  };

  // finish: convert + mean + LDS write into buffer `buf`
  auto finish = [&](int buf, int it, PG& p) {
    const int g = tid + it * 256;
    const int r = g / CHUNKS;
    const int c = (g - r * CHUNKS) * 8;
    uint4 xv, mv;
    if constexpr (SRCK == 0) {
      xv = make_uint4(cvtpk(p.s0.x, p.s0.y), cvtpk(p.s0.z, p.s0.w),
                      cvtpk(p.s1.x, p.s1.y), cvtpk(p.s1.z, p.s1.w));
      float4 m0, m1;
      m0.x = (p.a0.x + p.b0.x) + (p.c0.x + p.d0.x);
      m0.y = (p.a0.y + p.b0.y) + (p.c0.y + p.d0.y);
      m0.z = (p.a0.z + p.b0.z) + (p.c0.z + p.d0.z);
      m0.w = (p.a0.w + p.b0.w) + (p.c0.w + p.d0.w);
      m1.x = (p.a1.x + p.b1.x) + (p.c1.x + p.d1.x);
      m1.y = (p.a1.y + p.b1.y) + (p.c1.y + p.d1.y);
      m1.z = (p.a1.z + p.b1.z) + (p.c1.z + p.d1.z);
      m1.w = (p.a1.w + p.b1.w) + (p.c1.w + p.d1.w);
      mv = make_uint4(cvtpk(m0.x * 0.25f, m0.y * 0.25f), cvtpk(m0.z * 0.25f, m0.w * 0.25f),
                      cvtpk(m1.x * 0.25f, m1.y * 0.25f), cvtpk(m1.z * 0.25f, m1.w * 0.25f));
    } else {
      union { ushort8 s; uint4 u; } pun;       // bit-identical repack, 0 VALU
      pun.s = p.s;
      xv = pun.u;
      float sum[8];
      #pragma unroll
      for (int j = 0; j < 8; ++j)
        sum[j] = (bf2f(p.n0[j]) + bf2f(p.n1[j])) + (bf2f(p.n2[j]) + bf2f(p.n3[j]));
      mv = make_uint4(cvtpk(sum[0] * 0.25f, sum[1] * 0.25f), cvtpk(sum[2] * 0.25f, sum[3] * 0.25f),
                      cvtpk(sum[4] * 0.25f, sum[5] * 0.25f), cvtpk(sum[6] * 0.25f, sum[7] * 0.25f));
    }
    *reinterpret_cast<uint4*>(&As[buf][r][c]) = xv;
    *reinterpret_cast<uint4*>(&As[buf][r][FIN + c]) = mv;
  };

  // compute one staged tile from buf and store to global
  auto compute_store = [&](int buf, int node0) {
    f32x4 acc[RF][CF];
    #pragma unroll
    for (int rf = 0; rf < RF; ++rf)
      #pragma unroll
      for (int cf = 0; cf < CF; ++cf)
        acc[rf][cf] = (f32x4){bv[cf], bv[cf], bv[cf], bv[cf]};
    #pragma unroll
    for (int ks = 0; ks < KSTEPS; ++ks) {
      short8 a[RF];
      #pragma unroll
      for (int rf = 0; rf < RF; ++rf)
        a[rf] = *reinterpret_cast<const short8*>(&As[buf][rowbase + rf * 16 + fn][ks * 32 + fg * 8]);
      #pragma unroll
      for (int rf = 0; rf < RF; ++rf)
        #pragma unroll
        for (int cf = 0; cf < CF; ++cf)
          acc[rf][cf] = __builtin_amdgcn_mfma_f32_16x16x32_bf16(
              a[rf], Bfrag[ks][cf], acc[rf][cf], 0, 0, 0);
    }
    #pragma unroll
    for (int rf = 0; rf < RF; ++rf) {
      #pragma unroll
      for (int cf = 0; cf < CF; ++cf) {
        const int col = colbase + cf * 16 + fn;
        #pragma unroll
        for (int j = 0; j < 4; ++j) {
          const int row = rowbase + rf * 16 + fg * 4 + j;
          const int n = node0 + (row >> 2);
          const int b = row & 3;
          float v = acc[rf][cf][j];
          if (RELU) v = fmaxf(v, 0.f);
          if (DSTK == 0)
            ((float*)dstp)[((size_t)b * NNODES + n) * FOUT + col] = v;
          else
            ((unsigned short*)dstp)[((size_t)n * NB + b) * dstride + doff + col] = f2bf(v);
        }
      }
    }
  };

  const int bid = blockIdx.x;

  if constexpr (SRCK == 0) {
    // ---- depth-1 loop (champion, unchanged): fp32 source ----
    {
      PG p[ITERS];
      #pragma unroll
      for (int it = 0; it < ITERS; ++it) issue(bid * NPT, it, p[it]);
      #pragma unroll
      for (int it = 0; it < ITERS; ++it) finish(0, it, p[it]);
    }
    int cur = 0;
    for (int tile = bid; tile < NTILES; tile += GRID) {
      const bool hasnext = (tile + GRID) < NTILES;
      PG ptop[ITERS];
      if (hasnext) {
        #pragma unroll
        for (int it = 0; it < ITERS; ++it) issue((tile + GRID) * NPT, it, ptop[it]);
      }
      tile_barrier();
      compute_store(cur, tile * NPT);
      if (hasnext) {
        #pragma unroll
        for (int it = 0; it < ITERS; ++it) finish(cur ^ 1, it, ptop[it]);
      }
      cur ^= 1;
    }
  } else {
    // ---- depth-2 pair loop: bf16 source ----
    PG pA[ITERS], pB[ITERS];
    {
      PG p0[ITERS];
      #pragma unroll
      for (int it = 0; it < ITERS; ++it) issue(bid * NPT, it, p0[it]);
      #pragma unroll
      for (int it = 0; it < ITERS; ++it) finish(0, it, p0[it]);
    }
    #pragma unroll
    for (int it = 0; it < ITERS; ++it) issue((bid + GRID) * NPT, it, pA[it]);

    // invariant at loop top: buf0 = tile t0 staged, pA = tile t0+G in flight
    for (int k = 0; k < NPAIR; ++k) {
      const int t0 = bid + 2 * k * GRID;
      const bool last = (k == NPAIR - 1);

      if (!last) {
        #pragma unroll
        for (int it = 0; it < ITERS; ++it) issue((t0 + 2 * GRID) * NPT, it, pB[it]);
      }
      tile_barrier();
      compute_store(0, t0 * NPT);
      #pragma unroll
      for (int it = 0; it < ITERS; ++it) finish(1, it, pA[it]);    // tile t0+G

      if (!last) {
        #pragma unroll
        for (int it = 0; it < ITERS; ++it) issue((t0 + 3 * GRID) * NPT, it, pA[it]);
      }
      tile_barrier();
      compute_store(1, (t0 + GRID) * NPT);
      if (!last) {
        #pragma unroll
        for (int it = 0; it < ITERS; ++it) finish(0, it, pB[it]);  // tile t0+2G
      }
    }
  }
}

extern "C" void kernel_launch(void* const* d_in, const int* in_sizes, int n_in,
                              void* d_out, int out_size, void* d_ws, size_t ws_size,
                              hipStream_t stream) {
  const float* x  = (const float*)d_in[0];   // [B, N, 64] fp32
  const float* W1s = (const float*)d_in[2],  *W1n = (const float*)d_in[3],  *b1 = (const float*)d_in[4];
  const float* W2s = (const float*)d_in[5],  *W2n = (const float*)d_in[6],  *b2 = (const float*)d_in[7];
  const float* W3s = (const float*)d_in[8],  *W3n = (const float*)d_in[9],  *b3 = (const float*)d_in[10];
  const float* W4s = (const float*)d_in[11], *W4n = (const float*)d_in[12], *b4 = (const float*)d_in[13];
  const float* W5s = (const float*)d_in[14], *W5n = (const float*)d_in[15], *b5 = (const float*)d_in[16];
  const float* W6s = (const float*)d_in[17], *W6n = (const float*)d_in[18], *b6 = (const float*)d_in[19];

  // Buffers (bf16 intermediates, [N,B,stride] -- round-11 proven):
  //   h1   [N,B,128] bf16  -> d_out (exactly out bytes), dead after L2
  //   h6buf[N,B,128] bf16  -> d_ws   (h2 in cols 64:128, sage6-out in cols 0:64)
  //   h5buf[N,B, 64] bf16  -> d_out  (h3 in cols 32:64, sage5-out in cols 0:32)
  //   h4   [N,B, 32] bf16  -> d_out + 50.33MB
  unsigned short* h1 = (unsigned short*)d_out;
  unsigned short* h6 = (unsigned short*)d_ws;
  unsigned short* h5 = (unsigned short*)d_out;
  unsigned short* h4 = (unsigned short*)((char*)d_out + (size_t)NNODES * NB * 64 * 2);

  const dim3 block(256);

  // L1: x(fp32) -> h1 [*,128]
  sage_mfma<64, 128, 0, 1, true><<<dim3(grid_for(64, 0)), block, 0, stream>>>(x, 0, 0, h1, 128, 0, W1s, W1n, b1);
  // L2: h1 -> h2 = h6buf cols 64:128
  sage_mfma<128, 64, 1, 1, true><<<dim3(grid_for(128, 1)), block, 0, stream>>>(h1, 128, 0, h6, 128, 64, W2s, W2n, b2);
  // L3: h2 -> h3 = h5buf cols 32:64
  sage_mfma<64, 32, 1, 1, true><<<dim3(grid_for(64, 1)), block, 0, stream>>>(h6, 128, 64, h5, 64, 32, W3s, W3n, b3);
  // L4: h3 -> h4
  sage_mfma<32, 32, 1, 1, true><<<dim3(grid_for(32, 1)), block, 0, stream>>>(h5, 64, 32, h4, 32, 0, W4s, W4n, b4);
  // L5: h4 -> h5buf cols 0:32 (layer-4 weights reused, per reference)
  sage_mfma<32, 32, 1, 1, true><<<dim3(grid_for(32, 1)), block, 0, stream>>>(h4, 32, 0, h5, 64, 0, W4s, W4n, b4);
  // L6: h5 -> h6buf cols 0:64
  sage_mfma<64, 64, 1, 1, true><<<dim3(grid_for(64, 1)), block, 0, stream>>>(h5, 64, 0, h6, 128, 0, W5s, W5n, b5);
  // L7: h6 -> out fp32 [B,N,64], no relu
  sage_mfma<128, 64, 1, 0, false><<<dim3(grid_for(128, 1)), block, 0, stream>>>(h6, 128, 0, d_out, 0, 0, W6s, W6n, b6);
}

// Round 18
// 251.692 us; speedup vs baseline: 1.8139x; 1.8139x over previous
//
#include <hip/hip_runtime.h>
#include <type_traits>

#define NNODES 98304
#define NB 4
#define NX 128
#define FACE (NX * NX)

typedef __attribute__((ext_vector_type(8))) short short8;
typedef __attribute__((ext_vector_type(8))) unsigned short ushort8;
typedef __attribute__((ext_vector_type(4))) float f32x4;

__device__ __forceinline__ float bf2f(unsigned short u) {
  union { unsigned int u; float f; } c; c.u = ((unsigned int)u) << 16; return c.f;
}
__device__ __forceinline__ unsigned short f2bf(float f) {
  union { float f; unsigned int u; } c; c.f = f;
  unsigned int r = 0x7FFFu + ((c.u >> 16) & 1u);
  return (unsigned short)((c.u + r) >> 16);
}
// packed f32x2 -> bf16x2 (RNE); low16 = lo
__device__ __forceinline__ unsigned int cvtpk(float lo, float hi) {
  unsigned int r;
  asm("v_cvt_pk_bf16_f32 %0, %1, %2" : "=v"(r) : "v"(lo), "v"(hi));
  return r;
}

// Analytic 4-neighborhood (verified vs reference _build_neighbors).
__device__ __forceinline__ int4 nbr4(int n) {
  const int base = n & ~(FACE - 1);
  const int i = (n >> 7) & (NX - 1);
  const int j = n & (NX - 1);
  const int iu = (i + NX - 1) & (NX - 1), id = (i + 1) & (NX - 1);
  const int jl = (j + NX - 1) & (NX - 1), jr = (j + 1) & (NX - 1);
  return make_int4(base + (iu << 7) + j, base + (id << 7) + j,
                   base + (i << 7) + jl, base + (i << 7) + jr);
}

// lgkm-only tile barrier: prefetch global loads stay in flight across it.
__device__ __forceinline__ void tile_barrier() {
  asm volatile("s_waitcnt lgkmcnt(0)" ::: "memory");
  __builtin_amdgcn_s_barrier();
  asm volatile("" ::: "memory");
}

// Geometry / residency (round-11 proven values -- the 220us champion).
constexpr int rows_for(int FIN)            { return FIN == 32 ? 64 : 32; }
constexpr int grid_for(int FIN, int SRCK)  { return (FIN == 128 || SRCK == 0) ? 1024 : 1536; }
constexpr int minw_for(int FIN, int SRCK)  { return (FIN == 128 || SRCK == 0) ? 4 : 6; }

// Fused SAGE layer via MFMA: out = relu?( [X | mean4(X)] @ [Ws; Wn] + b ).
// Champion structure. DEPTH-2 prefetch ONLY where the prefetch state is one
// 40-VGPR struct per stage (SRCK==1 && ITERS==1, i.e. L3-L6): 2 stages = 80
// VGPR, fits the minw-6 cap (~84) without spill (round-12 measured 80).
// Round-17 lesson: depth-2 on ITERS=2 layers needs 160 VGPR -> spill ->
// 450MB of scratch traffic per dispatch. Those layers keep depth-1.
// SRCK: 0 = fp32 [B, N, FIN]; 1 = bf16 [N, B, sstride] + col offset soff.
// DSTK: 0 = fp32 [B, N, FOUT]; 1 = bf16 [N, B, dstride] + doff.
template<int FIN, int FOUT, int SRCK, int DSTK, bool RELU>
__global__ __launch_bounds__(256, minw_for(FIN, SRCK))
void sage_mfma(const void* __restrict__ srcp, int sstride, int soff,
               void* __restrict__ dstp, int dstride, int doff,
               const float* __restrict__ Ws, const float* __restrict__ Wn,
               const float* __restrict__ bias)
{
  constexpr int ROWS = rows_for(FIN);
  constexpr int GRID = grid_for(FIN, SRCK);
  constexpr int NPT = ROWS / 4;                  // nodes per tile
  constexpr int NTILES = (NNODES * NB) / ROWS;
  constexpr int NT = NTILES / GRID;              // 8 / 4 / 12 -- exact
  constexpr int K = 2 * FIN;
  constexpr int KSTEPS = K / 32;
  constexpr int LD = K + 8;                      // +16B pad (2-way conflict, free)
  constexpr int WAVES_N = (FOUT >= 64) ? 4 : 2;
  constexpr int WAVES_M = 4 / WAVES_N;
  constexpr int CF = FOUT / (16 * WAVES_N);
  constexpr int RF = ROWS / (16 * WAVES_M);
  constexpr int CHUNKS = FIN / 8;
  constexpr int ITERS = (ROWS * CHUNKS) / 256;   // 1 or 2 staging groups/thread
  constexpr bool DEPTH2 = (SRCK == 1) && (ITERS == 1);   // 80-VGPR budget only
  constexpr int NPAIR = NT / 2;

  __shared__ unsigned short As[2][ROWS][LD];

  const int tid = threadIdx.x;
  const int wave = tid >> 6, lane = tid & 63;
  const int wn = wave % WAVES_N, wm = wave / WAVES_N;
  const int colbase = wn * (FOUT / WAVES_N);
  const int rowbase = wm * (ROWS / WAVES_M);
  const int fn = lane & 15, fg = lane >> 4;

  // ---- weight fragments (B-operand = [Ws;Wn]), built once per block ----
  short8 Bfrag[KSTEPS][CF];
  float bv[CF];
  #pragma unroll
  for (int ks = 0; ks < KSTEPS; ++ks) {
    const float* wb = (ks * 32 < FIN) ? (Ws + (size_t)(ks * 32) * FOUT)
                                      : (Wn + (size_t)(ks * 32 - FIN) * FOUT);
    #pragma unroll
    for (int cf = 0; cf < CF; ++cf) {
      const int col = colbase + cf * 16 + fn;
      short8 f;
      #pragma unroll
      for (int j = 0; j < 8; ++j)
        f[j] = (short)f2bf(wb[(size_t)(fg * 8 + j) * FOUT + col]);
      Bfrag[ks][cf] = f;
    }
  }
  #pragma unroll
  for (int cf = 0; cf < CF; ++cf) bv[cf] = bias[colbase + cf * 16 + fn];

  struct G0 { float4 s0, s1, a0, a1, b0, b1, c0, c1, d0, d1; };
  struct G1 { ushort8 s, n0, n1, n2, n3; };
  using PG = typename std::conditional<SRCK == 0, G0, G1>::type;

  // issue: analytic neighbors + fire global loads (no waits)
  auto issue = [&](int node0, int it, PG& p) {
    const int g = tid + it * 256;
    const int r = g / CHUNKS;
    const int c = (g - r * CHUNKS) * 8;
    const int n = node0 + (r >> 2);
    const int b = r & 3;
    const int4 nb4 = nbr4(n);
    if constexpr (SRCK == 0) {
      const float* s = (const float*)srcp;
      const float* ps = s + ((size_t)b * NNODES + n) * FIN + c;
      const float* p0 = s + ((size_t)b * NNODES + nb4.x) * FIN + c;
      const float* p1 = s + ((size_t)b * NNODES + nb4.y) * FIN + c;
      const float* p2 = s + ((size_t)b * NNODES + nb4.z) * FIN + c;
      const float* p3 = s + ((size_t)b * NNODES + nb4.w) * FIN + c;
      p.s0 = *(const float4*)ps; p.s1 = *(const float4*)(ps + 4);
      p.a0 = *(const float4*)p0; p.a1 = *(const float4*)(p0 + 4);
      p.b0 = *(const float4*)p1; p.b1 = *(const float4*)(p1 + 4);
      p.c0 = *(const float4*)p2; p.c1 = *(const float4*)(p2 + 4);
      p.d0 = *(const float4*)p3; p.d1 = *(const float4*)(p3 + 4);
    } else {
      const unsigned short* s = (const unsigned short*)srcp;
      auto ld = [&](int nn) {
        return *reinterpret_cast<const ushort8*>(s + ((size_t)nn * NB + b) * sstride + soff + c);
      };
      p.s = ld(n); p.n0 = ld(nb4.x); p.n1 = ld(nb4.y); p.n2 = ld(nb4.z); p.n3 = ld(nb4.w);
    }
  };

  // finish: convert + mean + LDS write into buffer `buf`
  auto finish = [&](int buf, int it, PG& p) {
    const int g = tid + it * 256;
    const int r = g / CHUNKS;
    const int c = (g - r * CHUNKS) * 8;
    uint4 xv, mv;
    if constexpr (SRCK == 0) {
      xv = make_uint4(cvtpk(p.s0.x, p.s0.y), cvtpk(p.s0.z, p.s0.w),
                      cvtpk(p.s1.x, p.s1.y), cvtpk(p.s1.z, p.s1.w));
      float4 m0, m1;
      m0.x = (p.a0.x + p.b0.x) + (p.c0.x + p.d0.x);
      m0.y = (p.a0.y + p.b0.y) + (p.c0.y + p.d0.y);
      m0.z = (p.a0.z + p.b0.z) + (p.c0.z + p.d0.z);
      m0.w = (p.a0.w + p.b0.w) + (p.c0.w + p.d0.w);
      m1.x = (p.a1.x + p.b1.x) + (p.c1.x + p.d1.x);
      m1.y = (p.a1.y + p.b1.y) + (p.c1.y + p.d1.y);
      m1.z = (p.a1.z + p.b1.z) + (p.c1.z + p.d1.z);
      m1.w = (p.a1.w + p.b1.w) + (p.c1.w + p.d1.w);
      mv = make_uint4(cvtpk(m0.x * 0.25f, m0.y * 0.25f), cvtpk(m0.z * 0.25f, m0.w * 0.25f),
                      cvtpk(m1.x * 0.25f, m1.y * 0.25f), cvtpk(m1.z * 0.25f, m1.w * 0.25f));
    } else {
      union { ushort8 s; uint4 u; } pun;       // bit-identical repack, 0 VALU
      pun.s = p.s;
      xv = pun.u;
      float sum[8];
      #pragma unroll
      for (int j = 0; j < 8; ++j)
        sum[j] = (bf2f(p.n0[j]) + bf2f(p.n1[j])) + (bf2f(p.n2[j]) + bf2f(p.n3[j]));
      mv = make_uint4(cvtpk(sum[0] * 0.25f, sum[1] * 0.25f), cvtpk(sum[2] * 0.25f, sum[3] * 0.25f),
                      cvtpk(sum[4] * 0.25f, sum[5] * 0.25f), cvtpk(sum[6] * 0.25f, sum[7] * 0.25f));
    }
    *reinterpret_cast<uint4*>(&As[buf][r][c]) = xv;
    *reinterpret_cast<uint4*>(&As[buf][r][FIN + c]) = mv;
  };

  // compute one staged tile from buf and store to global
  auto compute_store = [&](int buf, int node0) {
    f32x4 acc[RF][CF];
    #pragma unroll
    for (int rf = 0; rf < RF; ++rf)
      #pragma unroll
      for (int cf = 0; cf < CF; ++cf)
        acc[rf][cf] = (f32x4){bv[cf], bv[cf], bv[cf], bv[cf]};
    #pragma unroll
    for (int ks = 0; ks < KSTEPS; ++ks) {
      short8 a[RF];
      #pragma unroll
      for (int rf = 0; rf < RF; ++rf)
        a[rf] = *reinterpret_cast<const short8*>(&As[buf][rowbase + rf * 16 + fn][ks * 32 + fg * 8]);
      #pragma unroll
      for (int rf = 0; rf < RF; ++rf)
        #pragma unroll
        for (int cf = 0; cf < CF; ++cf)
          acc[rf][cf] = __builtin_amdgcn_mfma_f32_16x16x32_bf16(
              a[rf], Bfrag[ks][cf], acc[rf][cf], 0, 0, 0);
    }
    #pragma unroll
    for (int rf = 0; rf < RF; ++rf) {
      #pragma unroll
      for (int cf = 0; cf < CF; ++cf) {
        const int col = colbase + cf * 16 + fn;
        #pragma unroll
        for (int j = 0; j < 4; ++j) {
          const int row = rowbase + rf * 16 + fg * 4 + j;
          const int n = node0 + (row >> 2);
          const int b = row & 3;
          float v = acc[rf][cf][j];
          if (RELU) v = fmaxf(v, 0.f);
          if (DSTK == 0)
            ((float*)dstp)[((size_t)b * NNODES + n) * FOUT + col] = v;
          else
            ((unsigned short*)dstp)[((size_t)n * NB + b) * dstride + doff + col] = f2bf(v);
        }
      }
    }
  };

  const int bid = blockIdx.x;

  if constexpr (!DEPTH2) {
    // ---- depth-1 loop (champion, unchanged): L1, L2, L7 ----
    {
      PG p[ITERS];
      #pragma unroll
      for (int it = 0; it < ITERS; ++it) issue(bid * NPT, it, p[it]);
      #pragma unroll
      for (int it = 0; it < ITERS; ++it) finish(0, it, p[it]);
    }
    int cur = 0;
    for (int tile = bid; tile < NTILES; tile += GRID) {
      const bool hasnext = (tile + GRID) < NTILES;
      PG ptop[ITERS];
      if (hasnext) {
        #pragma unroll
        for (int it = 0; it < ITERS; ++it) issue((tile + GRID) * NPT, it, ptop[it]);
      }
      tile_barrier();
      compute_store(cur, tile * NPT);
      if (hasnext) {
        #pragma unroll
        for (int it = 0; it < ITERS; ++it) finish(cur ^ 1, it, ptop[it]);
      }
      cur ^= 1;
    }
  } else {
    // ---- depth-2 pair loop: L3-L6 (one PG per stage, 80 VGPR total) ----
    PG pA, pB;
    {
      PG p0;
      issue(bid * NPT, 0, p0);
      finish(0, 0, p0);
    }
    issue((bid + GRID) * NPT, 0, pA);

    // invariant at loop top: buf0 = tile t0 staged, pA = tile t0+G in flight
    for (int k = 0; k < NPAIR; ++k) {
      const int t0 = bid + 2 * k * GRID;
      const bool last = (k == NPAIR - 1);

      if (!last) issue((t0 + 2 * GRID) * NPT, 0, pB);
      tile_barrier();
      compute_store(0, t0 * NPT);
      finish(1, 0, pA);                          // tile t0+G -> buf1

      if (!last) issue((t0 + 3 * GRID) * NPT, 0, pA);
      tile_barrier();
      compute_store(1, (t0 + GRID) * NPT);
      if (!last) finish(0, 0, pB);               // tile t0+2G -> buf0
    }
  }
}

extern "C" void kernel_launch(void* const* d_in, const int* in_sizes, int n_in,
                              void* d_out, int out_size, void* d_ws, size_t ws_size,
                              hipStream_t stream) {
  const float* x  = (const float*)d_in[0];   // [B, N, 64] fp32
  const float* W1s = (const float*)d_in[2],  *W1n = (const float*)d_in[3],  *b1 = (const float*)d_in[4];
  const float* W2s = (const float*)d_in[5],  *W2n = (const float*)d_in[6],  *b2 = (const float*)d_in[7];
  const float* W3s = (const float*)d_in[8],  *W3n = (const float*)d_in[9],  *b3 = (const float*)d_in[10];
  const float* W4s = (const float*)d_in[11], *W4n = (const float*)d_in[12], *b4 = (const float*)d_in[13];
  const float* W5s = (const float*)d_in[14], *W5n = (const float*)d_in[15], *b5 = (const float*)d_in[16];
  const float* W6s = (const float*)d_in[17], *W6n = (const float*)d_in[18], *b6 = (const float*)d_in[19];

  // Buffers (bf16 intermediates, [N,B,stride] -- round-11 proven):
  //   h1   [N,B,128] bf16  -> d_out (exactly out bytes), dead after L2
  //   h6buf[N,B,128] bf16  -> d_ws   (h2 in cols 64:128, sage6-out in cols 0:64)
  //   h5buf[N,B, 64] bf16  -> d_out  (h3 in cols 32:64, sage5-out in cols 0:32)
  //   h4   [N,B, 32] bf16  -> d_out + 50.33MB
  unsigned short* h1 = (unsigned short*)d_out;
  unsigned short* h6 = (unsigned short*)d_ws;
  unsigned short* h5 = (unsigned short*)d_out;
  unsigned short* h4 = (unsigned short*)((char*)d_out + (size_t)NNODES * NB * 64 * 2);

  const dim3 block(256);

  // L1: x(fp32) -> h1 [*,128]
  sage_mfma<64, 128, 0, 1, true><<<dim3(grid_for(64, 0)), block, 0, stream>>>(x, 0, 0, h1, 128, 0, W1s, W1n, b1);
  // L2: h1 -> h2 = h6buf cols 64:128
  sage_mfma<128, 64, 1, 1, true><<<dim3(grid_for(128, 1)), block, 0, stream>>>(h1, 128, 0, h6, 128, 64, W2s, W2n, b2);
  // L3: h2 -> h3 = h5buf cols 32:64
  sage_mfma<64, 32, 1, 1, true><<<dim3(grid_for(64, 1)), block, 0, stream>>>(h6, 128, 64, h5, 64, 32, W3s, W3n, b3);
  // L4: h3 -> h4
  sage_mfma<32, 32, 1, 1, true><<<dim3(grid_for(32, 1)), block, 0, stream>>>(h5, 64, 32, h4, 32, 0, W4s, W4n, b4);
  // L5: h4 -> h5buf cols 0:32 (layer-4 weights reused, per reference)
  sage_mfma<32, 32, 1, 1, true><<<dim3(grid_for(32, 1)), block, 0, stream>>>(h4, 32, 0, h5, 64, 0, W4s, W4n, b4);
  // L6: h5 -> h6buf cols 0:64
  sage_mfma<64, 64, 1, 1, true><<<dim3(grid_for(64, 1)), block, 0, stream>>>(h5, 64, 0, h6, 128, 0, W5s, W5n, b5);
  // L7: h6 -> out fp32 [B,N,64], no relu
  sage_mfma<128, 64, 1, 0, false><<<dim3(grid_for(128, 1)), block, 0, stream>>>(h6, 128, 0, d_out, 0, 0, W6s, W6n, b6);
}

// Round 19
// 219.120 us; speedup vs baseline: 2.0836x; 1.1486x over previous
//
#include <hip/hip_runtime.h>
#include <type_traits>

#define NNODES 98304
#define NB 4
#define NX 128
#define FACE (NX * NX)

typedef __attribute__((ext_vector_type(8))) short short8;
typedef __attribute__((ext_vector_type(8))) unsigned short ushort8;
typedef __attribute__((ext_vector_type(4))) float f32x4;

__device__ __forceinline__ float bf2f(unsigned short u) {
  union { unsigned int u; float f; } c; c.u = ((unsigned int)u) << 16; return c.f;
}
__device__ __forceinline__ unsigned short f2bf(float f) {
  union { float f; unsigned int u; } c; c.f = f;
  unsigned int r = 0x7FFFu + ((c.u >> 16) & 1u);
  return (unsigned short)((c.u + r) >> 16);
}
// packed f32x2 -> bf16x2 (RNE); low16 = lo
__device__ __forceinline__ unsigned int cvtpk(float lo, float hi) {
  unsigned int r;
  asm("v_cvt_pk_bf16_f32 %0, %1, %2" : "=v"(r) : "v"(lo), "v"(hi));
  return r;
}

// Analytic 4-neighborhood (verified vs reference _build_neighbors).
__device__ __forceinline__ int4 nbr4(int n) {
  const int base = n & ~(FACE - 1);
  const int i = (n >> 7) & (NX - 1);
  const int j = n & (NX - 1);
  const int iu = (i + NX - 1) & (NX - 1), id = (i + 1) & (NX - 1);
  const int jl = (j + NX - 1) & (NX - 1), jr = (j + 1) & (NX - 1);
  return make_int4(base + (iu << 7) + j, base + (id << 7) + j,
                   base + (i << 7) + jl, base + (i << 7) + jr);
}

// lgkm-only tile barrier: prefetch global loads stay in flight across it.
__device__ __forceinline__ void tile_barrier() {
  asm volatile("s_waitcnt lgkmcnt(0)" ::: "memory");
  __builtin_amdgcn_s_barrier();
  asm volatile("" ::: "memory");
}

// Geometry / residency (round-11 champion values).
constexpr int rows_for(int FIN)            { return FIN == 32 ? 64 : 32; }
constexpr int grid_for(int FIN, int SRCK)  { return (FIN == 128 || SRCK == 0) ? 1024 : 1536; }
constexpr int minw_for(int FIN, int SRCK)  { return (FIN == 128 || SRCK == 0) ? 4 : 6; }

// Fused SAGE layer via MFMA: out = relu?( [X | mean4(X)] @ [Ws; Wn] + b ).
// Champion structure: double-buffered LDS, ONE lgkm-only barrier per tile,
// depth-1 prefetch issued before the barrier, analytic neighbors.
// (Falsified levers, do not retry: depth-2 prefetch x3, occupancy push,
// XCD-chunked tiles, batch-major layout, full unroll, setprio, halo fusion.)
// SRCK: 0 = fp32 [B, N, FIN]; 1 = bf16 [N, B, sstride] + col offset soff.
// DSTK: 0 = fp32 [B, N, FOUT]; 1 = bf16 [N, B, dstride] + doff.
template<int FIN, int FOUT, int SRCK, int DSTK, bool RELU>
__global__ __launch_bounds__(256, minw_for(FIN, SRCK))
void sage_mfma(const void* __restrict__ srcp, int sstride, int soff,
               void* __restrict__ dstp, int dstride, int doff,
               const float* __restrict__ Ws, const float* __restrict__ Wn,
               const float* __restrict__ bias)
{
  constexpr int ROWS = rows_for(FIN);
  constexpr int GRID = grid_for(FIN, SRCK);
  constexpr int NPT = ROWS / 4;                  // nodes per tile
  constexpr int NTILES = (NNODES * NB) / ROWS;
  constexpr int K = 2 * FIN;                     // fused K: self | mean
  constexpr int KSTEPS = K / 32;
  constexpr int LD = K + 8;                      // +16B pad (2-way conflict, free)
  constexpr int WAVES_N = (FOUT >= 64) ? 4 : 2;
  constexpr int WAVES_M = 4 / WAVES_N;
  constexpr int CF = FOUT / (16 * WAVES_N);      // col frags per wave
  constexpr int RF = ROWS / (16 * WAVES_M);      // row frags per wave
  constexpr int CHUNKS = FIN / 8;
  constexpr int ITERS = (ROWS * CHUNKS) / 256;   // staging groups per thread (1 or 2)
  constexpr int PF = ITERS;

  __shared__ unsigned short As[2][ROWS][LD];

  const int tid = threadIdx.x;
  const int wave = tid >> 6, lane = tid & 63;
  const int wn = wave % WAVES_N, wm = wave / WAVES_N;
  const int colbase = wn * (FOUT / WAVES_N);
  const int rowbase = wm * (ROWS / WAVES_M);
  const int fn = lane & 15, fg = lane >> 4;

  // ---- weight fragments (B-operand = [Ws;Wn]), built once per block ----
  short8 Bfrag[KSTEPS][CF];
  float bv[CF];
  #pragma unroll
  for (int ks = 0; ks < KSTEPS; ++ks) {
    const float* wb = (ks * 32 < FIN) ? (Ws + (size_t)(ks * 32) * FOUT)
                                      : (Wn + (size_t)(ks * 32 - FIN) * FOUT);
    #pragma unroll
    for (int cf = 0; cf < CF; ++cf) {
      const int col = colbase + cf * 16 + fn;
      short8 f;
      #pragma unroll
      for (int j = 0; j < 8; ++j)
        f[j] = (short)f2bf(wb[(size_t)(fg * 8 + j) * FOUT + col]);
      Bfrag[ks][cf] = f;
    }
  }
  #pragma unroll
  for (int cf = 0; cf < CF; ++cf) bv[cf] = bias[colbase + cf * 16 + fn];

  struct G0 { float4 s0, s1, a0, a1, b0, b1, c0, c1, d0, d1; };
  struct G1 { ushort8 s, n0, n1, n2, n3; };
  using PG = typename std::conditional<SRCK == 0, G0, G1>::type;

  // issue: analytic neighbors + fire global loads (no nbr-table round trip)
  auto issue = [&](int node0, int it, PG& p) {
    const int g = tid + it * 256;
    const int r = g / CHUNKS;
    const int c = (g - r * CHUNKS) * 8;
    const int n = node0 + (r >> 2);
    const int b = r & 3;
    const int4 nb4 = nbr4(n);
    if constexpr (SRCK == 0) {
      const float* s = (const float*)srcp;
      const float* ps = s + ((size_t)b * NNODES + n) * FIN + c;
      const float* p0 = s + ((size_t)b * NNODES + nb4.x) * FIN + c;
      const float* p1 = s + ((size_t)b * NNODES + nb4.y) * FIN + c;
      const float* p2 = s + ((size_t)b * NNODES + nb4.z) * FIN + c;
      const float* p3 = s + ((size_t)b * NNODES + nb4.w) * FIN + c;
      p.s0 = *(const float4*)ps; p.s1 = *(const float4*)(ps + 4);
      p.a0 = *(const float4*)p0; p.a1 = *(const float4*)(p0 + 4);
      p.b0 = *(const float4*)p1; p.b1 = *(const float4*)(p1 + 4);
      p.c0 = *(const float4*)p2; p.c1 = *(const float4*)(p2 + 4);
      p.d0 = *(const float4*)p3; p.d1 = *(const float4*)(p3 + 4);
    } else {
      const unsigned short* s = (const unsigned short*)srcp;
      auto ld = [&](int nn) {
        return *reinterpret_cast<const ushort8*>(s + ((size_t)nn * NB + b) * sstride + soff + c);
      };
      p.s = ld(n); p.n0 = ld(nb4.x); p.n1 = ld(nb4.y); p.n2 = ld(nb4.z); p.n3 = ld(nb4.w);
    }
  };

  // finish: convert + mean + LDS write into buffer `buf`
  auto finish = [&](int buf, int it, PG& p) {
    const int g = tid + it * 256;
    const int r = g / CHUNKS;
    const int c = (g - r * CHUNKS) * 8;
    uint4 xv, mv;
    if constexpr (SRCK == 0) {
      xv = make_uint4(cvtpk(p.s0.x, p.s0.y), cvtpk(p.s0.z, p.s0.w),
                      cvtpk(p.s1.x, p.s1.y), cvtpk(p.s1.z, p.s1.w));
      float4 m0, m1;
      m0.x = (p.a0.x + p.b0.x) + (p.c0.x + p.d0.x);
      m0.y = (p.a0.y + p.b0.y) + (p.c0.y + p.d0.y);
      m0.z = (p.a0.z + p.b0.z) + (p.c0.z + p.d0.z);
      m0.w = (p.a0.w + p.b0.w) + (p.c0.w + p.d0.w);
      m1.x = (p.a1.x + p.b1.x) + (p.c1.x + p.d1.x);
      m1.y = (p.a1.y + p.b1.y) + (p.c1.y + p.d1.y);
      m1.z = (p.a1.z + p.b1.z) + (p.c1.z + p.d1.z);
      m1.w = (p.a1.w + p.b1.w) + (p.c1.w + p.d1.w);
      mv = make_uint4(cvtpk(m0.x * 0.25f, m0.y * 0.25f), cvtpk(m0.z * 0.25f, m0.w * 0.25f),
                      cvtpk(m1.x * 0.25f, m1.y * 0.25f), cvtpk(m1.z * 0.25f, m1.w * 0.25f));
    } else {
      union { ushort8 s; uint4 u; } pun;       // bit-identical repack, 0 VALU
      pun.s = p.s;
      xv = pun.u;
      float sum[8];
      #pragma unroll
      for (int j = 0; j < 8; ++j)
        sum[j] = (bf2f(p.n0[j]) + bf2f(p.n1[j])) + (bf2f(p.n2[j]) + bf2f(p.n3[j]));
      mv = make_uint4(cvtpk(sum[0] * 0.25f, sum[1] * 0.25f), cvtpk(sum[2] * 0.25f, sum[3] * 0.25f),
                      cvtpk(sum[4] * 0.25f, sum[5] * 0.25f), cvtpk(sum[6] * 0.25f, sum[7] * 0.25f));
    }
    *reinterpret_cast<uint4*>(&As[buf][r][c]) = xv;
    *reinterpret_cast<uint4*>(&As[buf][r][FIN + c]) = mv;
  };

  // ---- prologue: stage first tile into buf 0 ----
  {
    PG p[ITERS];
    #pragma unroll
    for (int it = 0; it < ITERS; ++it) issue(blockIdx.x * NPT, it, p[it]);
    #pragma unroll
    for (int it = 0; it < ITERS; ++it) finish(0, it, p[it]);
  }

  // ---- main loop: one lgkm-only barrier per tile ----
  int cur = 0;
  for (int tile = blockIdx.x; tile < NTILES; tile += GRID) {
    const int node0 = tile * NPT;
    const bool hasnext = (tile + GRID) < NTILES;
    const int nnode0 = (tile + GRID) * NPT;

    PG ptop[PF];
    if (hasnext) {
      #pragma unroll
      for (int it = 0; it < PF; ++it) issue(nnode0, it, ptop[it]);
    }

    tile_barrier();   // buf[cur] ds_writes visible; prefetch loads UNAFFECTED

    f32x4 acc[RF][CF];
    #pragma unroll
    for (int rf = 0; rf < RF; ++rf)
      #pragma unroll
      for (int cf = 0; cf < CF; ++cf)
        acc[rf][cf] = (f32x4){bv[cf], bv[cf], bv[cf], bv[cf]};

    #pragma unroll
    for (int ks = 0; ks < KSTEPS; ++ks) {
      short8 a[RF];
      #pragma unroll
      for (int rf = 0; rf < RF; ++rf)
        a[rf] = *reinterpret_cast<const short8*>(&As[cur][rowbase + rf * 16 + fn][ks * 32 + fg * 8]);
      #pragma unroll
      for (int rf = 0; rf < RF; ++rf)
        #pragma unroll
        for (int cf = 0; cf < CF; ++cf)
          acc[rf][cf] = __builtin_amdgcn_mfma_f32_16x16x32_bf16(
              a[rf], Bfrag[ks][cf], acc[rf][cf], 0, 0, 0);
    }

    // ---- store (C/D map: col = lane&15, row = (lane>>4)*4 + j) ----
    #pragma unroll
    for (int rf = 0; rf < RF; ++rf) {
      #pragma unroll
      for (int cf = 0; cf < CF; ++cf) {
        const int col = colbase + cf * 16 + fn;
        #pragma unroll
        for (int j = 0; j < 4; ++j) {
          const int row = rowbase + rf * 16 + fg * 4 + j;
          const int n = node0 + (row >> 2);
          const int b = row & 3;
          float v = acc[rf][cf][j];
          if (RELU) v = fmaxf(v, 0.f);
          if (DSTK == 0)
            ((float*)dstp)[((size_t)b * NNODES + n) * FOUT + col] = v;
          else
            ((unsigned short*)dstp)[((size_t)n * NB + b) * dstride + doff + col] = f2bf(v);
        }
      }
    }

    // ---- stage next tile into the other buffer (no extra barrier) ----
    if (hasnext) {
      #pragma unroll
      for (int it = 0; it < PF; ++it) finish(cur ^ 1, it, ptop[it]);
    }
    cur ^= 1;
  }
}

extern "C" void kernel_launch(void* const* d_in, const int* in_sizes, int n_in,
                              void* d_out, int out_size, void* d_ws, size_t ws_size,
                              hipStream_t stream) {
  const float* x  = (const float*)d_in[0];   // [B, N, 64] fp32
  const float* W1s = (const float*)d_in[2],  *W1n = (const float*)d_in[3],  *b1 = (const float*)d_in[4];
  const float* W2s = (const float*)d_in[5],  *W2n = (const float*)d_in[6],  *b2 = (const float*)d_in[7];
  const float* W3s = (const float*)d_in[8],  *W3n = (const float*)d_in[9],  *b3 = (const float*)d_in[10];
  const float* W4s = (const float*)d_in[11], *W4n = (const float*)d_in[12], *b4 = (const float*)d_in[13];
  const float* W5s = (const float*)d_in[14], *W5n = (const float*)d_in[15], *b5 = (const float*)d_in[16];
  const float* W6s = (const float*)d_in[17], *W6n = (const float*)d_in[18], *b6 = (const float*)d_in[19];

  // Buffers (bf16 intermediates, [N,B,stride]):
  //   h1   [N,B,128] bf16  -> d_out (exactly out bytes), dead after L2
  //   h6buf[N,B,128] bf16  -> d_ws   (h2 in cols 64:128, sage6-out in cols 0:64)
  //   h5buf[N,B, 64] bf16  -> d_out  (h3 in cols 32:64, sage5-out in cols 0:32)
  //   h4   [N,B, 32] bf16  -> d_out + 50.33MB
  unsigned short* h1 = (unsigned short*)d_out;
  unsigned short* h6 = (unsigned short*)d_ws;
  unsigned short* h5 = (unsigned short*)d_out;
  unsigned short* h4 = (unsigned short*)((char*)d_out + (size_t)NNODES * NB * 64 * 2);

  const dim3 block(256);

  // L1: x(fp32) -> h1 [*,128]
  sage_mfma<64, 128, 0, 1, true><<<dim3(grid_for(64, 0)), block, 0, stream>>>(x, 0, 0, h1, 128, 0, W1s, W1n, b1);
  // L2: h1 -> h2 = h6buf cols 64:128
  sage_mfma<128, 64, 1, 1, true><<<dim3(grid_for(128, 1)), block, 0, stream>>>(h1, 128, 0, h6, 128, 64, W2s, W2n, b2);
  // L3: h2 -> h3 = h5buf cols 32:64
  sage_mfma<64, 32, 1, 1, true><<<dim3(grid_for(64, 1)), block, 0, stream>>>(h6, 128, 64, h5, 64, 32, W3s, W3n, b3);
  // L4: h3 -> h4
  sage_mfma<32, 32, 1, 1, true><<<dim3(grid_for(32, 1)), block, 0, stream>>>(h5, 64, 32, h4, 32, 0, W4s, W4n, b4);
  // L5: h4 -> h5buf cols 0:32 (layer-4 weights reused, per reference)
  sage_mfma<32, 32, 1, 1, true><<<dim3(grid_for(32, 1)), block, 0, stream>>>(h4, 32, 0, h5, 64, 0, W4s, W4n, b4);
  // L6: h5 -> h6buf cols 0:64
  sage_mfma<64, 64, 1, 1, true><<<dim3(grid_for(64, 1)), block, 0, stream>>>(h5, 64, 0, h6, 128, 0, W5s, W5n, b5);
  // L7: h6 -> out fp32 [B,N,64], no relu
  sage_mfma<128, 64, 1, 0, false><<<dim3(grid_for(128, 1)), block, 0, stream>>>(h6, 128, 0, d_out, 0, 0, W6s, W6n, b6);
}